// Round 1
// baseline (1235.258 us; speedup 1.0000x reference)
//
#include <hip/hip_runtime.h>

static constexpr int NN   = 100000;   // nodes
static constexpr int NE   = 1600000;  // edges (without self loops)
static constexpr int ET   = NE + NN;  // edges + self loops
static constexpr int NG   = 512;      // graphs
static constexpr int INF_ = 16;
static constexpr int HID  = 64;
#define NEG_SLOPE 0.2f

// monotone float<->uint key for atomicMax over signed floats; key(-inf)=0x007FFFFF>0,
// so memset(0) is a safe "empty" sentinel (every node has a self-loop anyway).
__device__ __forceinline__ unsigned fkey(float f) {
  unsigned b = __float_as_uint(f);
  return (b & 0x80000000u) ? ~b : (b | 0x80000000u);
}
__device__ __forceinline__ float funkey(unsigned k) {
  unsigned b = (k & 0x80000000u) ? (k & 0x7fffffffu) : ~k;
  return __uint_as_float(b);
}
__device__ __forceinline__ float lrelu(float x) { return x > 0.f ? x : NEG_SLOPE * x; }

// ---------- layer-1 node transform: h = relu(x) @ W1, a_src/a_dst dots ----------
__global__ __launch_bounds__(256) void k_node1(
    const float* __restrict__ x, const float* __restrict__ W,
    const float* __restrict__ atts, const float* __restrict__ attd,
    float* __restrict__ h, float* __restrict__ a_s, float* __restrict__ a_d)
{
  __shared__ float Ws[INF_][HID];
  __shared__ float xs[4][INF_];
  const int tid = threadIdx.x;
  for (int i = tid; i < INF_ * HID; i += 256) Ws[i / HID][i % HID] = W[i];
  const int wv = tid >> 6, ln = tid & 63;
  const int n = blockIdx.x * 4 + wv;
  if (n < NN && ln < INF_) {
    float v = x[n * INF_ + ln];
    xs[wv][ln] = v > 0.f ? v : 0.f;
  }
  __syncthreads();
  if (n >= NN) return;
  float acc = 0.f;
#pragma unroll
  for (int k = 0; k < INF_; ++k) acc += xs[wv][k] * Ws[k][ln];
  h[n * HID + ln] = acc;
  float as = acc * atts[ln], ad = acc * attd[ln];
#pragma unroll
  for (int o = 32; o > 0; o >>= 1) { as += __shfl_xor(as, o); ad += __shfl_xor(ad, o); }
  if (ln == 0) { a_s[n] = as; a_d[n] = ad; }
}

// ---------- layer-2 node transform: h2 = relu(agg/den + b1) @ W2 ----------
__global__ __launch_bounds__(256) void k_node2(
    const float* __restrict__ agg, const float* __restrict__ den,
    const float* __restrict__ bias, const float* __restrict__ W,
    const float* __restrict__ atts, const float* __restrict__ attd,
    float* __restrict__ h, float* __restrict__ a_s, float* __restrict__ a_d)
{
  __shared__ float Ws[HID][HID];   // 16 KB
  __shared__ float xs[4][HID];
  const int tid = threadIdx.x;
  for (int i = tid; i < HID * HID; i += 256) Ws[i / HID][i % HID] = W[i];
  const int wv = tid >> 6, ln = tid & 63;
  const int n = blockIdx.x * 4 + wv;
  if (n < NN) {
    float dn = den[n] + 1e-16f;
    float v = agg[n * HID + ln] / dn + bias[ln];
    xs[wv][ln] = v > 0.f ? v : 0.f;
  }
  __syncthreads();
  if (n >= NN) return;
  float acc = 0.f;
#pragma unroll
  for (int k = 0; k < HID; ++k) acc += xs[wv][k] * Ws[k][ln];
  h[n * HID + ln] = acc;
  float as = acc * atts[ln], ad = acc * attd[ln];
#pragma unroll
  for (int o = 32; o > 0; o >>= 1) { as += __shfl_xor(as, o); ad += __shfl_xor(ad, o); }
  if (ln == 0) { a_s[n] = as; a_d[n] = ad; }
}

// ---------- per-edge segment max of leaky-relu logits ----------
__global__ __launch_bounds__(256) void k_edge_max(
    const int* __restrict__ ei, const float* __restrict__ a_s,
    const float* __restrict__ a_d, unsigned* __restrict__ mk)
{
  int e = blockIdx.x * 256 + threadIdx.x;
  if (e >= ET) return;
  int s, d;
  if (e < NE) { s = ei[e]; d = ei[NE + e]; } else { s = d = e - NE; }
  float l = lrelu(a_s[s] + a_d[d]);
  atomicMax(&mk[d], fkey(l));
}

// ---------- per-edge exp + unnormalized aggregate (wave per edge) ----------
__global__ __launch_bounds__(256) void k_edge_agg(
    const int* __restrict__ ei, const float* __restrict__ a_s,
    const float* __restrict__ a_d, const unsigned* __restrict__ mk,
    const float* __restrict__ h, float* __restrict__ agg, float* __restrict__ den)
{
  const int e  = blockIdx.x * 4 + (threadIdx.x >> 6);
  const int ln = threadIdx.x & 63;
  if (e >= ET) return;
  int s, d;
  if (e < NE) { s = ei[e]; d = ei[NE + e]; } else { s = d = e - NE; }
  float l  = lrelu(a_s[s] + a_d[d]);
  float ev = __expf(l - funkey(mk[d]));
  if (ln == 0) unsafeAtomicAdd(&den[d], ev);
  unsafeAtomicAdd(&agg[d * HID + ln], h[s * HID + ln] * ev);
}

// ---------- pooling: finalize conv2 (norm+bias+relu) + per-graph max/sum ----------
__global__ __launch_bounds__(256) void k_pool(
    const float* __restrict__ agg, const float* __restrict__ den,
    const float* __restrict__ bias, const int* __restrict__ batch,
    unsigned* __restrict__ gmax, float* __restrict__ gsum, unsigned* __restrict__ cnt)
{
  const int wv = threadIdx.x >> 6, ln = threadIdx.x & 63;
  const int base = (blockIdx.x * 4 + wv) * 64;
  if (base >= NN) return;
  const int end = min(NN, base + 64);
  float b = bias[ln];
  float rmax = 0.f, rsum = 0.f;
  int cg = batch[base], run = 0;
  for (int n = base; n < end; ++n) {
    int g = batch[n];
    if (g != cg) {
      atomicMax(&gmax[cg * HID + ln], __float_as_uint(rmax));  // relu -> >=0
      unsafeAtomicAdd(&gsum[cg * HID + ln], rsum);
      if (ln == 0) atomicAdd(&cnt[cg], (unsigned)run);
      rmax = 0.f; rsum = 0.f; run = 0; cg = g;
    }
    float v = agg[n * HID + ln] / (den[n] + 1e-16f) + b;
    v = v > 0.f ? v : 0.f;
    rmax = fmaxf(rmax, v); rsum += v; ++run;
  }
  atomicMax(&gmax[cg * HID + ln], __float_as_uint(rmax));
  unsafeAtomicAdd(&gsum[cg * HID + ln], rsum);
  if (ln == 0) atomicAdd(&cnt[cg], (unsigned)run);
}

// ---------- head: [gmax | gmean] @ fc_w + fc_b ----------
__global__ __launch_bounds__(256) void k_final(
    const unsigned* __restrict__ gmax, const float* __restrict__ gsum,
    const unsigned* __restrict__ cnt, const float* __restrict__ fcw,
    const float* __restrict__ fcb, float* __restrict__ out)
{
  const int wv = threadIdx.x >> 6, ln = threadIdx.x & 63;
  const int g = blockIdx.x * 4 + wv;
  if (g >= NG) return;
  float c = (float)cnt[g];
  float mx = __uint_as_float(gmax[g * HID + ln]);
  float mean = gsum[g * HID + ln] / fmaxf(c, 1.f);
  float v = mx * fcw[ln] + mean * fcw[HID + ln];
#pragma unroll
  for (int o = 32; o > 0; o >>= 1) v += __shfl_xor(v, o);
  if (ln == 0) out[g] = v + fcb[0];
}

extern "C" void kernel_launch(void* const* d_in, const int* in_sizes, int n_in,
                              void* d_out, int out_size, void* d_ws, size_t ws_size,
                              hipStream_t stream)
{
  const float* x    = (const float*)d_in[0];
  const int*   ei   = (const int*)d_in[1];
  const int*   batch= (const int*)d_in[2];
  const float* W1   = (const float*)d_in[3];
  const float* as1  = (const float*)d_in[4];
  const float* ad1  = (const float*)d_in[5];
  const float* b1   = (const float*)d_in[6];
  const float* W2   = (const float*)d_in[7];
  const float* as2  = (const float*)d_in[8];
  const float* ad2  = (const float*)d_in[9];
  const float* b2   = (const float*)d_in[10];
  const float* fcw  = (const float*)d_in[11];
  const float* fcb  = (const float*)d_in[12];
  float* out = (float*)d_out;

  float* h     = (float*)d_ws;                    // NN*HID
  float* agg   = h + (size_t)NN * HID;            // NN*HID
  float* a_s   = agg + (size_t)NN * HID;          // NN
  float* a_d   = a_s + NN;                        // NN
  float* den   = a_d + NN;                        // NN
  unsigned* mk = (unsigned*)(den + NN);           // NN
  unsigned* gmax = mk + NN;                       // NG*HID
  float* gsum  = (float*)(gmax + NG * HID);       // NG*HID
  unsigned* cnt = (unsigned*)(gsum + NG * HID);   // NG

  // ---- layer 1 ----
  hipMemsetAsync(agg, 0, sizeof(float) * (size_t)NN * HID, stream);
  hipMemsetAsync(den, 0, sizeof(float) * NN, stream);
  hipMemsetAsync(mk,  0, sizeof(unsigned) * NN, stream);
  k_node1<<<NN / 4, 256, 0, stream>>>(x, W1, as1, ad1, h, a_s, a_d);
  k_edge_max<<<(ET + 255) / 256, 256, 0, stream>>>(ei, a_s, a_d, mk);
  k_edge_agg<<<ET / 4, 256, 0, stream>>>(ei, a_s, a_d, mk, h, agg, den);

  // ---- layer 2 transform consumes agg/den, then re-zero accumulators ----
  k_node2<<<NN / 4, 256, 0, stream>>>(agg, den, b1, W2, as2, ad2, h, a_s, a_d);
  hipMemsetAsync(agg, 0, sizeof(float) * (size_t)NN * HID, stream);
  hipMemsetAsync(den, 0, sizeof(float) * NN, stream);
  hipMemsetAsync(mk,  0, sizeof(unsigned) * NN, stream);
  k_edge_max<<<(ET + 255) / 256, 256, 0, stream>>>(ei, a_s, a_d, mk);
  k_edge_agg<<<ET / 4, 256, 0, stream>>>(ei, a_s, a_d, mk, h, agg, den);

  // ---- pooling + head ----
  hipMemsetAsync(gmax, 0, sizeof(unsigned) * NG * HID, stream);
  hipMemsetAsync(gsum, 0, sizeof(float) * NG * HID, stream);
  hipMemsetAsync(cnt,  0, sizeof(unsigned) * NG, stream);
  k_pool<<<(NN + 255) / 256, 256, 0, stream>>>(agg, den, b2, batch, gmax, gsum, cnt);
  k_final<<<NG / 4, 256, 0, stream>>>(gmax, gsum, cnt, fcw, fcb, out);
}

// Round 2
// 565.954 us; speedup vs baseline: 2.1826x; 2.1826x over previous
//
#include <hip/hip_runtime.h>

static constexpr int NN   = 100000;   // nodes
static constexpr int NE   = 1600000;  // edges (without self loops)
static constexpr int ET   = NE + NN;  // edges + self loops
static constexpr int NG   = 512;      // graphs
static constexpr int INF_ = 16;
static constexpr int HID  = 64;
static constexpr int NBLK = (NN + 1023) / 1024;   // scan blocks (98)
#define NEG_SLOPE 0.2f

__device__ __forceinline__ float lrelu(float x) { return x > 0.f ? x : NEG_SLOPE * x; }

// ---------- layer-1 node transform: h = relu(x) @ W1, a_src/a_dst dots ----------
__global__ __launch_bounds__(256) void k_node1(
    const float* __restrict__ x, const float* __restrict__ W,
    const float* __restrict__ atts, const float* __restrict__ attd,
    float* __restrict__ h, float* __restrict__ a_s, float* __restrict__ a_d)
{
  __shared__ float Ws[INF_][HID];
  __shared__ float xs[4][INF_];
  const int tid = threadIdx.x;
  for (int i = tid; i < INF_ * HID; i += 256) Ws[i / HID][i % HID] = W[i];
  const int wv = tid >> 6, ln = tid & 63;
  const int n = blockIdx.x * 4 + wv;
  if (ln < INF_) {
    float v = x[n * INF_ + ln];
    xs[wv][ln] = v > 0.f ? v : 0.f;
  }
  __syncthreads();
  float acc = 0.f;
#pragma unroll
  for (int k = 0; k < INF_; ++k) acc += xs[wv][k] * Ws[k][ln];
  h[n * HID + ln] = acc;
  float as = acc * atts[ln], ad = acc * attd[ln];
#pragma unroll
  for (int o = 32; o > 0; o >>= 1) { as += __shfl_xor(as, o); ad += __shfl_xor(ad, o); }
  if (ln == 0) { a_s[n] = as; a_d[n] = ad; }
}

// ---------- layer-2 node transform: h2 = act1 @ W2 (act1 already relu'd) ----------
__global__ __launch_bounds__(256) void k_node2(
    const float* __restrict__ act, const float* __restrict__ W,
    const float* __restrict__ atts, const float* __restrict__ attd,
    float* __restrict__ h, float* __restrict__ a_s, float* __restrict__ a_d)
{
  __shared__ float Ws[HID][HID];   // 16 KB
  __shared__ float xs[4][HID];
  const int tid = threadIdx.x;
  for (int i = tid; i < HID * HID; i += 256) Ws[i / HID][i % HID] = W[i];
  const int wv = tid >> 6, ln = tid & 63;
  const int n = blockIdx.x * 4 + wv;
  xs[wv][ln] = act[n * HID + ln];
  __syncthreads();
  float acc = 0.f;
#pragma unroll
  for (int k = 0; k < HID; ++k) acc += xs[wv][k] * Ws[k][ln];
  h[n * HID + ln] = acc;
  float as = acc * atts[ln], ad = acc * attd[ln];
#pragma unroll
  for (int o = 32; o > 0; o >>= 1) { as += __shfl_xor(as, o); ad += __shfl_xor(ad, o); }
  if (ln == 0) { a_s[n] = as; a_d[n] = ad; }
}

// ---------- CSR build: degree histogram ----------
__global__ __launch_bounds__(256) void k_hist(const int* __restrict__ ei,
                                              unsigned* __restrict__ deg)
{
  int e = blockIdx.x * 256 + threadIdx.x;
  if (e >= ET) return;
  int d = (e < NE) ? ei[NE + e] : e - NE;
  atomicAdd(&deg[d], 1u);
}

// ---------- scan pass 1: per-block (1024-elem) sums ----------
__global__ __launch_bounds__(256) void k_scan_bsum(const unsigned* __restrict__ deg,
                                                   unsigned* __restrict__ bsum)
{
  __shared__ unsigned red[4];
  const int t = threadIdx.x;
  const int base = blockIdx.x * 1024 + t * 4;
  unsigned s = 0;
#pragma unroll
  for (int k = 0; k < 4; ++k) { int i = base + k; if (i < NN) s += deg[i]; }
#pragma unroll
  for (int o = 32; o > 0; o >>= 1) s += __shfl_xor(s, o);
  if ((t & 63) == 0) red[t >> 6] = s;
  __syncthreads();
  if (t == 0) bsum[blockIdx.x] = red[0] + red[1] + red[2] + red[3];
}

// ---------- scan pass 2: exclusive scan of block sums (single wave) ----------
__global__ __launch_bounds__(64) void k_scan_boff(unsigned* __restrict__ bsum)
{
  const int ln = threadIdx.x;
  unsigned carry = 0;
  for (int base = 0; base < NBLK; base += 64) {
    int i = base + ln;
    unsigned orig = (i < NBLK) ? bsum[i] : 0;
    unsigned v = orig;
#pragma unroll
    for (int o = 1; o < 64; o <<= 1) { unsigned tv = __shfl_up(v, o); if (ln >= o) v += tv; }
    if (i < NBLK) bsum[i] = carry + v - orig;
    carry += __shfl(v, 63);
  }
}

// ---------- scan pass 3: write rowptr (exclusive) + cursor copy ----------
__global__ __launch_bounds__(256) void k_scan_write(
    const unsigned* __restrict__ deg, const unsigned* __restrict__ bsum,
    unsigned* __restrict__ rowptr, unsigned* __restrict__ cursor)
{
  __shared__ unsigned wsum[4];
  const int t = threadIdx.x;
  const int base = blockIdx.x * 1024 + t * 4;
  unsigned d[4]; unsigned s = 0;
#pragma unroll
  for (int k = 0; k < 4; ++k) { int i = base + k; d[k] = (i < NN) ? deg[i] : 0; s += d[k]; }
  unsigned v = s;
#pragma unroll
  for (int o = 1; o < 64; o <<= 1) { unsigned tv = __shfl_up(v, o); if ((t & 63) >= o) v += tv; }
  if ((t & 63) == 63) wsum[t >> 6] = v;
  __syncthreads();
  unsigned woff = 0;
  for (int w = 0; w < (t >> 6); ++w) woff += wsum[w];
  unsigned excl = woff + (v - s) + bsum[blockIdx.x];
#pragma unroll
  for (int k = 0; k < 4; ++k) {
    int i = base + k;
    if (i < NN) { rowptr[i] = excl; cursor[i] = excl; }
    excl += d[k];
  }
}

// ---------- CSR build: scatter src ids into dst buckets ----------
__global__ __launch_bounds__(256) void k_scatter(const int* __restrict__ ei,
                                                 unsigned* __restrict__ cursor,
                                                 int* __restrict__ es)
{
  int e = blockIdx.x * 256 + threadIdx.x;
  if (e >= ET) return;
  int s, d;
  if (e < NE) { s = ei[e]; d = ei[NE + e]; } else { s = d = e - NE; }
  unsigned pos = atomicAdd(&cursor[d], 1u);
  es[pos] = s;
}

// ---------- gather-style GAT aggregate: wave per dst node, no atomics ----------
__global__ __launch_bounds__(256) void k_gather(
    const int* __restrict__ es, const unsigned* __restrict__ rowptr,
    const unsigned* __restrict__ deg, const float* __restrict__ a_s,
    const float* __restrict__ a_d, const float* __restrict__ h,
    const float* __restrict__ bias, float* __restrict__ act)
{
  const int wv = threadIdx.x >> 6, ln = threadIdx.x & 63;
  const int n = blockIdx.x * 4 + wv;
  const unsigned beg = rowptr[n];
  const unsigned end = beg + deg[n];
  const float ad = a_d[n];
  // phase 1: segment max (lane-parallel over edges)
  float m = -1e30f;
  for (unsigned j = beg + ln; j < end; j += 64) {
    int s = es[j];
    m = fmaxf(m, lrelu(a_s[s] + ad));
  }
#pragma unroll
  for (int o = 32; o > 0; o >>= 1) m = fmaxf(m, __shfl_xor(m, o));
  // phase 2: serial over edges, lane-parallel over features
  float acc = 0.f, den = 0.f;
  unsigned j = beg;
  for (; j + 1 < end; j += 2) {
    int s0 = es[j], s1 = es[j + 1];
    float e0 = __expf(lrelu(a_s[s0] + ad) - m);
    float e1 = __expf(lrelu(a_s[s1] + ad) - m);
    float h0 = h[(size_t)s0 * HID + ln];
    float h1 = h[(size_t)s1 * HID + ln];
    den += e0 + e1;
    acc += h0 * e0 + h1 * e1;
  }
  if (j < end) {
    int s0 = es[j];
    float e0 = __expf(lrelu(a_s[s0] + ad) - m);
    den += e0;
    acc += h[(size_t)s0 * HID + ln] * e0;
  }
  float v = acc / (den + 1e-16f) + bias[ln];
  act[n * HID + ln] = v > 0.f ? v : 0.f;
}

// ---------- pooling: per-graph max/sum over finalized act2 ----------
__global__ __launch_bounds__(256) void k_pool(
    const float* __restrict__ act, const int* __restrict__ batch,
    unsigned* __restrict__ gmax, float* __restrict__ gsum, unsigned* __restrict__ cnt)
{
  const int wv = threadIdx.x >> 6, ln = threadIdx.x & 63;
  const int base = (blockIdx.x * 4 + wv) * 64;
  if (base >= NN) return;
  const int end = min(NN, base + 64);
  float rmax = 0.f, rsum = 0.f;
  int cg = batch[base], run = 0;
  for (int n = base; n < end; ++n) {
    int g = batch[n];
    if (g != cg) {
      atomicMax(&gmax[cg * HID + ln], __float_as_uint(rmax));  // relu -> >=0
      unsafeAtomicAdd(&gsum[cg * HID + ln], rsum);
      if (ln == 0) atomicAdd(&cnt[cg], (unsigned)run);
      rmax = 0.f; rsum = 0.f; run = 0; cg = g;
    }
    float v = act[n * HID + ln];
    rmax = fmaxf(rmax, v); rsum += v; ++run;
  }
  atomicMax(&gmax[cg * HID + ln], __float_as_uint(rmax));
  unsafeAtomicAdd(&gsum[cg * HID + ln], rsum);
  if (ln == 0) atomicAdd(&cnt[cg], (unsigned)run);
}

// ---------- head: [gmax | gmean] @ fc_w + fc_b ----------
__global__ __launch_bounds__(256) void k_final(
    const unsigned* __restrict__ gmax, const float* __restrict__ gsum,
    const unsigned* __restrict__ cnt, const float* __restrict__ fcw,
    const float* __restrict__ fcb, float* __restrict__ out)
{
  const int wv = threadIdx.x >> 6, ln = threadIdx.x & 63;
  const int g = blockIdx.x * 4 + wv;
  if (g >= NG) return;
  float c = (float)cnt[g];
  float mx = __uint_as_float(gmax[g * HID + ln]);
  float mean = gsum[g * HID + ln] / fmaxf(c, 1.f);
  float v = mx * fcw[ln] + mean * fcw[HID + ln];
#pragma unroll
  for (int o = 32; o > 0; o >>= 1) v += __shfl_xor(v, o);
  if (ln == 0) out[g] = v + fcb[0];
}

extern "C" void kernel_launch(void* const* d_in, const int* in_sizes, int n_in,
                              void* d_out, int out_size, void* d_ws, size_t ws_size,
                              hipStream_t stream)
{
  const float* x    = (const float*)d_in[0];
  const int*   ei   = (const int*)d_in[1];
  const int*   batch= (const int*)d_in[2];
  const float* W1   = (const float*)d_in[3];
  const float* as1  = (const float*)d_in[4];
  const float* ad1  = (const float*)d_in[5];
  const float* b1   = (const float*)d_in[6];
  const float* W2   = (const float*)d_in[7];
  const float* as2  = (const float*)d_in[8];
  const float* ad2  = (const float*)d_in[9];
  const float* b2   = (const float*)d_in[10];
  const float* fcw  = (const float*)d_in[11];
  const float* fcb  = (const float*)d_in[12];
  float* out = (float*)d_out;

  float* h        = (float*)d_ws;                  // NN*HID
  float* act      = h + (size_t)NN * HID;          // NN*HID
  float* a_s      = act + (size_t)NN * HID;        // NN
  float* a_d      = a_s + NN;                      // NN
  unsigned* deg   = (unsigned*)(a_d + NN);         // NN
  unsigned* rowptr= deg + NN;                      // NN
  unsigned* cursor= rowptr + NN;                   // NN
  unsigned* bsum  = cursor + NN;                   // NBLK (pad 128)
  int* es         = (int*)(bsum + 128);            // ET
  unsigned* gmax  = (unsigned*)(es + ET);          // NG*HID
  float* gsum     = (float*)(gmax + NG * HID);     // NG*HID
  unsigned* cnt   = (unsigned*)(gsum + NG * HID);  // NG

  const int egrid = (ET + 255) / 256;

  // ---- CSR build (topology shared by both layers) ----
  hipMemsetAsync(deg, 0, sizeof(unsigned) * NN, stream);
  k_hist<<<egrid, 256, 0, stream>>>(ei, deg);
  k_scan_bsum<<<NBLK, 256, 0, stream>>>(deg, bsum);
  k_scan_boff<<<1, 64, 0, stream>>>(bsum);
  k_scan_write<<<NBLK, 256, 0, stream>>>(deg, bsum, rowptr, cursor);
  k_scatter<<<egrid, 256, 0, stream>>>(ei, cursor, es);

  // ---- layer 1 ----
  k_node1<<<NN / 4, 256, 0, stream>>>(x, W1, as1, ad1, h, a_s, a_d);
  k_gather<<<NN / 4, 256, 0, stream>>>(es, rowptr, deg, a_s, a_d, h, b1, act);

  // ---- layer 2 ----
  k_node2<<<NN / 4, 256, 0, stream>>>(act, W2, as2, ad2, h, a_s, a_d);
  k_gather<<<NN / 4, 256, 0, stream>>>(es, rowptr, deg, a_s, a_d, h, b2, act);

  // ---- pooling + head ----
  hipMemsetAsync(gmax, 0, sizeof(unsigned) * NG * HID, stream);
  hipMemsetAsync(gsum, 0, sizeof(float) * NG * HID, stream);
  hipMemsetAsync(cnt,  0, sizeof(unsigned) * NG, stream);
  k_pool<<<(NN + 255) / 256, 256, 0, stream>>>(act, batch, gmax, gsum, cnt);
  k_final<<<NG / 4, 256, 0, stream>>>(gmax, gsum, cnt, fcw, fcb, out);
}